// Round 10
// baseline (172.174 us; speedup 1.0000x reference)
//
#include <hip/hip_runtime.h>
#include <stdint.h>

#define NTOK 4096
#define HDIM 1024
#define DDIM 2048
#define NEXP 8
#define NASS 8192   // NTOK * K (K=2)

typedef __attribute__((ext_vector_type(8))) short bf16x8;
typedef __attribute__((ext_vector_type(4))) float f32x4;

typedef __attribute__((address_space(1))) const unsigned int gu32;
typedef __attribute__((address_space(3))) unsigned int lu32;

// barrier that is ALSO a compiler memory fence (raw builtin is not; R5 raced)
#define BARRIER() asm volatile("s_barrier" ::: "memory")
#define WAIT_VM0() asm volatile("s_waitcnt vmcnt(0)" ::: "memory")
#define WAIT_LGKM0() do { asm volatile("s_waitcnt lgkmcnt(0)" ::: "memory"); \
                          __builtin_amdgcn_sched_barrier(0); } while (0)

__device__ __forceinline__ void async16(void* lds, const void* g) {
  __builtin_amdgcn_global_load_lds((gu32*)(uintptr_t)g, (lu32*)(uintptr_t)lds, 16, 0, 0);
}

__device__ __forceinline__ unsigned short f2bf(float f) {
  unsigned int u = __float_as_uint(f);
  return (unsigned short)((u + 0x7fffu + ((u >> 16) & 1u)) >> 16);
}
__device__ __forceinline__ float bf2f(unsigned short u) {
  return __uint_as_float(((unsigned int)u) << 16);
}

// ---------------- x fp32 -> bf16 ----------------
__global__ __launch_bounds__(256) void k_cvt_x(const float* __restrict__ x,
                                               unsigned short* __restrict__ x16) {
  int i = blockIdx.x * 256 + threadIdx.x;
  float4 v = reinterpret_cast<const float4*>(x)[i];
  ushort4 o;
  o.x = f2bf(v.x); o.y = f2bf(v.y); o.z = f2bf(v.z); o.w = f2bf(v.w);
  reinterpret_cast<ushort4*>(x16)[i] = o;
}

// ---------------- [E][R][C] fp32 -> [E][C][R] bf16 (tiled transpose) ----------------
__global__ __launch_bounds__(256) void k_transpose(const float* __restrict__ in,
                                                   unsigned short* __restrict__ out,
                                                   int R, int C) {
  __shared__ float t[32][33];
  const size_t mbase = (size_t)blockIdx.z * R * C;
  int tid = threadIdx.x;
  int r = tid >> 3, c4 = (tid & 7) * 4;
  int gr = blockIdx.y * 32 + r;
  int gc = blockIdx.x * 32 + c4;
  float4 v = *reinterpret_cast<const float4*>(in + mbase + (size_t)gr * C + gc);
  t[r][c4 + 0] = v.x; t[r][c4 + 1] = v.y; t[r][c4 + 2] = v.z; t[r][c4 + 3] = v.w;
  __syncthreads();
  int orow = blockIdx.x * 32 + r;    // original col
  int oc4  = blockIdx.y * 32 + c4;   // original row
  ushort4 o;
  o.x = f2bf(t[c4 + 0][r]); o.y = f2bf(t[c4 + 1][r]);
  o.z = f2bf(t[c4 + 2][r]); o.w = f2bf(t[c4 + 3][r]);
  *reinterpret_cast<ushort4*>(out + mbase + (size_t)orow * R + oc4) = o;
}

// ---------------- routing: detect+count+scan+scatter in ONE block ----------------
__global__ __launch_bounds__(1024) void k_route(
    const int* __restrict__ idx, const float* __restrict__ ew,
    const int* __restrict__ amask,
    int* __restrict__ counts_g, int* __restrict__ offs_g,
    int* __restrict__ toks, float* __restrict__ wl, int* __restrict__ slotmap) {
  __shared__ int cnt[NEXP], cur[NEXP], flag;
  const int t = threadIdx.x;
  if (t < NEXP) cnt[t] = 0;
  if (t == 0) flag = 0;
  __syncthreads();
  // dtype detect: if int64, all high (odd) words are 0
  int lf = 0;
#pragma unroll
  for (int j = 0; j < 4; ++j) {
    int i = t + j * 1024;
    if (idx[2 * i + 1] != 0) lf = 1;
  }
  if (lf) atomicOr(&flag, 1);
  __syncthreads();
  const int is32 = flag;
  int e[8];
#pragma unroll
  for (int j = 0; j < 8; ++j) {
    int i = t + j * 1024;
    int ei = is32 ? idx[i] : idx[2 * i];
    e[j] = ei;
    atomicAdd(&cnt[ei], 1);
  }
  __syncthreads();
  if (t == 0) {
    int off = 0;
    for (int k = 0; k < NEXP; ++k) {
      cur[k] = off; offs_g[k] = off; counts_g[k] = cnt[k]; off += cnt[k];
    }
  }
  __syncthreads();
#pragma unroll
  for (int j = 0; j < 8; ++j) {
    int i = t + j * 1024;
    int n = i >> 1;
    int slot = atomicAdd(&cur[e[j]], 1);
    toks[slot] = n;
    wl[slot] = ew[i] * (amask[n] ? 1.0f : 0.0f);
    slotmap[i] = slot;
  }
}

// ---------------- grouped GEMM1: hid = relu(X[gather] @ down) ----------------
// 256x256 tile, BK=64, 512 thr / 8 waves (2M x 4N), per-wave 128x64 (acc[8][4]):
// 2.67 MFMA per ds_read_b128 -> MFMA-bound K-loop (R9 was LDS-read-bound at 1.33).
// Dbuf 128KB LDS, 1 block/CU. Single barrier + single vmcnt(0) per K-tile (proven).
// Expert->XCD colocation: blockIdx.x == XCD == expert.
__global__ __launch_bounds__(512, 2) void k_gemm_down(
    const unsigned short* __restrict__ x16, const unsigned short* __restrict__ bT,
    const int* __restrict__ counts, const int* __restrict__ offs,
    const int* __restrict__ toks, unsigned short* __restrict__ hid) {
  const int e = blockIdx.x;                 // expert == XCD
  const int cnt = counts[e];
  const int q = blockIdx.y;                 // 0..127
  const int mt = q >> 3;                    // 0..15 (covers cnt up to 4096)
  const int nt = q & 7;                     // 0..7  (DDIM/256)
  if (mt * 256 >= cnt) return;
  const int base = offs[e];
  __shared__ alignas(16) char lds[131072];  // A: 2x32KB @0, B: 2x32KB @65536
  const int tid = threadIdx.x;
  const int lane = tid & 63;
  const int wr = ((tid >> 8) & 1) * 128;    // wave M block (2)
  const int wc = ((tid >> 6) & 3) * 64;     // wave N block (4)

  // staging: LDS linear [256 rows][128B]; global col pre-swizzled so
  // LDS[row][c] = G[row][c ^ ((row&7)<<4)]   (rule #21)
  const char* gA[4]; const char* gB[4]; int sOff[4];
  {
    const int swcol = ((tid & 7) << 4) ^ (((tid >> 3) & 7) << 4);
#pragma unroll
    for (int s = 0; s < 4; ++s) {
      int row = s * 64 + (tid >> 3);
      int sl = mt * 256 + row; if (sl >= cnt) sl = cnt - 1;
      gA[s] = (const char*)(x16 + (size_t)toks[base + sl] * HDIM) + swcol;
      gB[s] = (const char*)(bT + (size_t)e * DDIM * HDIM + (size_t)(nt * 256 + row) * HDIM) + swcol;
      sOff[s] = s * 8192 + tid * 16;
    }
  }
  const int swz = (lane & 7) << 4;
  const int lo = (lane >> 4) << 4;
  int rowA[8], rowB[4];
#pragma unroll
  for (int m = 0; m < 8; ++m) rowA[m] = (wr + m * 16 + (lane & 15)) * 128;
#pragma unroll
  for (int n = 0; n < 4; ++n) rowB[n] = (wc + n * 16 + (lane & 15)) * 128;

  // prologue: stage K-tile 0 into buf0
#pragma unroll
  for (int s = 0; s < 4; ++s) {
    async16(lds + sOff[s], gA[s]);
    async16(lds + 65536 + sOff[s], gB[s]);
  }

  f32x4 acc[8][4] = {};
  for (int j = 0; j < 16; ++j) {
    WAIT_VM0();   // tile j's 8 loads landed (issued during tile j-1)
    BARRIER();    // all waves done reading buf[(j-1)&1]
    char* curA = lds + ((j & 1) << 15);
    char* curB = lds + 65536 + ((j & 1) << 15);
    if (j < 15) {
      const int ko = (j + 1) << 7;
      char* nA = lds + ((~j & 1) << 15);
      char* nB = lds + 65536 + ((~j & 1) << 15);
#pragma unroll
      for (int s = 0; s < 4; ++s) {
        async16(nA + sOff[s], gA[s] + ko);
        async16(nB + sOff[s], gB[s] + ko);
      }
    }
#pragma unroll
    for (int ks = 0; ks < 2; ++ks) {
      const int cx = ((ks << 6) | lo) ^ swz;
      bf16x8 fa[8], fb[4];
#pragma unroll
      for (int n = 0; n < 4; ++n) fb[n] = *reinterpret_cast<const bf16x8*>(curB + rowB[n] + cx);
#pragma unroll
      for (int m = 0; m < 8; ++m) fa[m] = *reinterpret_cast<const bf16x8*>(curA + rowA[m] + cx);
      WAIT_LGKM0();
      __builtin_amdgcn_s_setprio(1);
#pragma unroll
      for (int m = 0; m < 8; ++m)
#pragma unroll
        for (int n = 0; n < 4; ++n)
          acc[m][n] = __builtin_amdgcn_mfma_f32_16x16x32_bf16(fa[m], fb[n], acc[m][n], 0, 0, 0);
      __builtin_amdgcn_s_setprio(0);
    }
  }

#pragma unroll
  for (int m = 0; m < 8; ++m) {
    int r0 = mt * 256 + wr + m * 16 + ((lane >> 4) * 4);
#pragma unroll
    for (int jj = 0; jj < 4; ++jj) {
      int r = r0 + jj;
      if (r < cnt) {
        unsigned short* dst = hid + (size_t)(base + r) * DDIM + nt * 256 + wc + (lane & 15);
#pragma unroll
        for (int n = 0; n < 4; ++n) {
          float v = acc[m][n][jj];
          dst[n * 16] = f2bf(v > 0.f ? v : 0.f);
        }
      }
    }
  }
}

// ---------------- grouped GEMM2 (K-split 2): yw[ksp][slot] = partial(hid @ up) ----------------
// Same 256x256 geometry; K=1024 per split -> 16 K-tiles; 32 active tiles/XCD.
__global__ __launch_bounds__(512, 2) void k_gemm_up(
    const unsigned short* __restrict__ hid, const unsigned short* __restrict__ bT,
    const int* __restrict__ counts, const int* __restrict__ offs,
    unsigned short* __restrict__ yw) {
  const int e = blockIdx.x;                 // expert == XCD
  const int cnt = counts[e];
  const int q = blockIdx.y;                 // 0..127
  const int nt = q & 3;                     // 0..3 (HDIM/256)
  const int mt = (q >> 2) & 15;             // 0..15
  const int ksp = q >> 6;                   // 0..1
  if (mt * 256 >= cnt) return;
  const int base = offs[e];
  __shared__ alignas(16) char lds[131072];
  const int tid = threadIdx.x;
  const int lane = tid & 63;
  const int wr = ((tid >> 8) & 1) * 128;
  const int wc = ((tid >> 6) & 3) * 64;

  const char* gA[4]; const char* gB[4]; int sOff[4];
  {
    const int swcol = ((tid & 7) << 4) ^ (((tid >> 3) & 7) << 4);
#pragma unroll
    for (int s = 0; s < 4; ++s) {
      int row = s * 64 + (tid >> 3);
      int sl = mt * 256 + row; if (sl >= cnt) sl = cnt - 1;
      gA[s] = (const char*)(hid + (size_t)(base + sl) * DDIM + ksp * 1024) + swcol;
      gB[s] = (const char*)(bT + (size_t)e * HDIM * DDIM + (size_t)(nt * 256 + row) * DDIM + ksp * 1024) + swcol;
      sOff[s] = s * 8192 + tid * 16;
    }
  }
  const int swz = (lane & 7) << 4;
  const int lo = (lane >> 4) << 4;
  int rowA[8], rowB[4];
#pragma unroll
  for (int m = 0; m < 8; ++m) rowA[m] = (wr + m * 16 + (lane & 15)) * 128;
#pragma unroll
  for (int n = 0; n < 4; ++n) rowB[n] = (wc + n * 16 + (lane & 15)) * 128;

#pragma unroll
  for (int s = 0; s < 4; ++s) {
    async16(lds + sOff[s], gA[s]);
    async16(lds + 65536 + sOff[s], gB[s]);
  }

  f32x4 acc[8][4] = {};
  for (int j = 0; j < 16; ++j) {
    WAIT_VM0();
    BARRIER();
    char* curA = lds + ((j & 1) << 15);
    char* curB = lds + 65536 + ((j & 1) << 15);
    if (j < 15) {
      const int ko = (j + 1) << 7;
      char* nA = lds + ((~j & 1) << 15);
      char* nB = lds + 65536 + ((~j & 1) << 15);
#pragma unroll
      for (int s = 0; s < 4; ++s) {
        async16(nA + sOff[s], gA[s] + ko);
        async16(nB + sOff[s], gB[s] + ko);
      }
    }
#pragma unroll
    for (int ks = 0; ks < 2; ++ks) {
      const int cx = ((ks << 6) | lo) ^ swz;
      bf16x8 fa[8], fb[4];
#pragma unroll
      for (int n = 0; n < 4; ++n) fb[n] = *reinterpret_cast<const bf16x8*>(curB + rowB[n] + cx);
#pragma unroll
      for (int m = 0; m < 8; ++m) fa[m] = *reinterpret_cast<const bf16x8*>(curA + rowA[m] + cx);
      WAIT_LGKM0();
      __builtin_amdgcn_s_setprio(1);
#pragma unroll
      for (int m = 0; m < 8; ++m)
#pragma unroll
        for (int n = 0; n < 4; ++n)
          acc[m][n] = __builtin_amdgcn_mfma_f32_16x16x32_bf16(fa[m], fb[n], acc[m][n], 0, 0, 0);
      __builtin_amdgcn_s_setprio(0);
    }
  }

#pragma unroll
  for (int m = 0; m < 8; ++m) {
    int r0 = mt * 256 + wr + m * 16 + ((lane >> 4) * 4);
#pragma unroll
    for (int jj = 0; jj < 4; ++jj) {
      int r = r0 + jj;
      if (r < cnt) {
        unsigned short* dst = yw + ((size_t)ksp * NASS + base + r) * HDIM
                              + nt * 256 + wc + (lane & 15);
#pragma unroll
        for (int n = 0; n < 4; ++n) dst[n * 16] = f2bf(acc[m][n][jj]);
      }
    }
  }
}

// ---------------- combine: out = x + w0*(p00+p01) + w1*(p10+p11) ----------------
__global__ __launch_bounds__(256) void k_combine(
    const float* __restrict__ x, const unsigned short* __restrict__ yw,
    const int* __restrict__ slotmap, const float* __restrict__ wl,
    float* __restrict__ out) {
  const int n = blockIdx.x;
  const int t = threadIdx.x;
  const int s0 = slotmap[2 * n], s1 = slotmap[2 * n + 1];
  const float w0 = wl[s0], w1 = wl[s1];
  float4 xv = reinterpret_cast<const float4*>(x + (size_t)n * HDIM)[t];
  ushort4 a0 = reinterpret_cast<const ushort4*>(yw + (size_t)s0 * HDIM)[t];
  ushort4 a1 = reinterpret_cast<const ushort4*>(yw + ((size_t)NASS + s0) * HDIM)[t];
  ushort4 b0 = reinterpret_cast<const ushort4*>(yw + (size_t)s1 * HDIM)[t];
  ushort4 b1 = reinterpret_cast<const ushort4*>(yw + ((size_t)NASS + s1) * HDIM)[t];
  float4 r;
  r.x = xv.x + w0 * (bf2f(a0.x) + bf2f(a1.x)) + w1 * (bf2f(b0.x) + bf2f(b1.x));
  r.y = xv.y + w0 * (bf2f(a0.y) + bf2f(a1.y)) + w1 * (bf2f(b0.y) + bf2f(b1.y));
  r.z = xv.z + w0 * (bf2f(a0.z) + bf2f(a1.z)) + w1 * (bf2f(b0.z) + bf2f(b1.z));
  r.w = xv.w + w0 * (bf2f(a0.w) + bf2f(a1.w)) + w1 * (bf2f(b0.w) + bf2f(b1.w));
  reinterpret_cast<float4*>(out + (size_t)n * HDIM)[t] = r;
}

extern "C" void kernel_launch(void* const* d_in, const int* in_sizes, int n_in,
                              void* d_out, int out_size, void* d_ws, size_t ws_size,
                              hipStream_t stream) {
  const float* x    = (const float*)d_in[0];
  const int* amask  = (const int*)d_in[1];
  const float* ew   = (const float*)d_in[2];
  const int* cidx   = (const int*)d_in[3];
  const float* dn   = (const float*)d_in[4];
  const float* up   = (const float*)d_in[5];
  float* out        = (float*)d_out;
  char* ws          = (char*)d_ws;

  const size_t X16_OFF = 0;
  const size_t DNT_OFF = X16_OFF + (size_t)NTOK * HDIM * 2;             // 8.4MB
  const size_t UPT_OFF = DNT_OFF + (size_t)NEXP * HDIM * DDIM * 2;      // +33.5MB
  const size_t HID_OFF = UPT_OFF + (size_t)NEXP * HDIM * DDIM * 2;      // +33.5MB
  const size_t MET_OFF = HID_OFF + (size_t)NASS * DDIM * 2;             // +33.5MB

  unsigned short* x16 = (unsigned short*)(ws + X16_OFF);
  unsigned short* dnT = (unsigned short*)(ws + DNT_OFF);
  unsigned short* upT = (unsigned short*)(ws + UPT_OFF);
  unsigned short* hid = (unsigned short*)(ws + HID_OFF);
  // yw ([2][NASS][HDIM] bf16, 33.5MB) aliases dnT: dnT dead after k_gemm_down
  unsigned short* yw  = (unsigned short*)(ws + DNT_OFF);
  int* counts  = (int*)(ws + MET_OFF);
  int* offs    = counts + 8;
  int* toks    = counts + 32;
  float* wl    = (float*)(toks + NASS);
  int* slotmap = (int*)(wl + NASS);

  k_cvt_x<<<NTOK * HDIM / 1024, 256, 0, stream>>>(x, x16);
  k_transpose<<<dim3(DDIM / 32, HDIM / 32, NEXP), 256, 0, stream>>>(dn, dnT, HDIM, DDIM);
  k_transpose<<<dim3(HDIM / 32, DDIM / 32, NEXP), 256, 0, stream>>>(up, upT, DDIM, HDIM);
  k_route<<<1, 1024, 0, stream>>>(cidx, ew, amask, counts, offs, toks, wl, slotmap);
  // blockIdx.x == XCD id (round-robin dispatch) == expert id
  k_gemm_down<<<dim3(8, 128), 512, 0, stream>>>(x16, dnT, counts, offs, toks, hid);
  k_gemm_up<<<dim3(8, 128), 512, 0, stream>>>(hid, upT, counts, offs, yw);
  k_combine<<<NTOK, 256, 0, stream>>>(x, yw, slotmap, wl, out);
}

// Round 11
// 156.512 us; speedup vs baseline: 1.1001x; 1.1001x over previous
//
#include <hip/hip_runtime.h>
#include <stdint.h>

#define NTOK 4096
#define HDIM 1024
#define DDIM 2048
#define NEXP 8
#define NASS 8192   // NTOK * K (K=2)

typedef __attribute__((ext_vector_type(8))) short bf16x8;
typedef __attribute__((ext_vector_type(4))) float f32x4;

typedef __attribute__((address_space(1))) const unsigned int gu32;
typedef __attribute__((address_space(3))) unsigned int lu32;

// barrier that is ALSO a compiler memory fence (raw builtin is not; R5 raced)
#define BARRIER() asm volatile("s_barrier" ::: "memory")
#define WAIT_VM0() asm volatile("s_waitcnt vmcnt(0)" ::: "memory")
#define WAIT_LGKM0() do { asm volatile("s_waitcnt lgkmcnt(0)" ::: "memory"); \
                          __builtin_amdgcn_sched_barrier(0); } while (0)

__device__ __forceinline__ void async16(void* lds, const void* g) {
  __builtin_amdgcn_global_load_lds((gu32*)(uintptr_t)g, (lu32*)(uintptr_t)lds, 16, 0, 0);
}

__device__ __forceinline__ unsigned short f2bf(float f) {
  unsigned int u = __float_as_uint(f);
  return (unsigned short)((u + 0x7fffu + ((u >> 16) & 1u)) >> 16);
}
__device__ __forceinline__ float bf2f(unsigned short u) {
  return __uint_as_float(((unsigned int)u) << 16);
}

// ---------------- prep: cvt_x + transpose(dn) + transpose(up) in ONE launch ----------------
// blocks [0,4096): x fp32 -> bf16
// blocks [4096, 4096+16384): dn [E][1024][2048] -> dnT [E][2048][1024] bf16
// blocks [20480, 20480+16384): up [E][2048][1024] -> upT [E][1024][2048] bf16
__device__ __forceinline__ void transpose_tile(const float* __restrict__ in,
                                               unsigned short* __restrict__ out,
                                               int R, int C, int e, int bx, int by,
                                               float* tb, int tid) {
  const size_t mbase = (size_t)e * R * C;
  int r = tid >> 3, c4 = (tid & 7) * 4;
  int gr = by * 32 + r;
  int gc = bx * 32 + c4;
  float4 v = *reinterpret_cast<const float4*>(in + mbase + (size_t)gr * C + gc);
  tb[r * 33 + c4 + 0] = v.x; tb[r * 33 + c4 + 1] = v.y;
  tb[r * 33 + c4 + 2] = v.z; tb[r * 33 + c4 + 3] = v.w;
  __syncthreads();
  int orow = bx * 32 + r;
  int oc4  = by * 32 + c4;
  ushort4 o;
  o.x = f2bf(tb[(c4 + 0) * 33 + r]); o.y = f2bf(tb[(c4 + 1) * 33 + r]);
  o.z = f2bf(tb[(c4 + 2) * 33 + r]); o.w = f2bf(tb[(c4 + 3) * 33 + r]);
  *reinterpret_cast<ushort4*>(out + mbase + (size_t)orow * R + oc4) = o;
}

__global__ __launch_bounds__(256) void k_prep(
    const float* __restrict__ x, unsigned short* __restrict__ x16,
    const float* __restrict__ dn, unsigned short* __restrict__ dnT,
    const float* __restrict__ up, unsigned short* __restrict__ upT) {
  __shared__ float tb[32 * 33];
  const int b = blockIdx.x;
  const int tid = threadIdx.x;
  if (b < 4096) {
    int i = b * 256 + tid;
    float4 v = reinterpret_cast<const float4*>(x)[i];
    ushort4 o;
    o.x = f2bf(v.x); o.y = f2bf(v.y); o.z = f2bf(v.z); o.w = f2bf(v.w);
    reinterpret_cast<ushort4*>(x16)[i] = o;
  } else if (b < 4096 + 16384) {
    // dn: R=1024 rows, C=2048 cols; tiles per expert = 32x64 = 2048
    int idx = b - 4096;
    int e = idx >> 11, t = idx & 2047;
    int bx = t & 63, by = t >> 6;       // bx over C/32=64, by over R/32=32
    transpose_tile(dn, dnT, HDIM, DDIM, e, bx, by, tb, tid);
  } else {
    // up: R=2048 rows, C=1024 cols; tiles per expert = 64x32 = 2048
    int idx = b - 20480;
    int e = idx >> 11, t = idx & 2047;
    int bx = t & 31, by = t >> 5;       // bx over C/32=32, by over R/32=64
    transpose_tile(up, upT, DDIM, HDIM, e, bx, by, tb, tid);
  }
}

// ---------------- routing: detect+count+scan+scatter in ONE block ----------------
__global__ __launch_bounds__(1024) void k_route(
    const int* __restrict__ idx, const float* __restrict__ ew,
    const int* __restrict__ amask,
    int* __restrict__ counts_g, int* __restrict__ offs_g,
    int* __restrict__ toks, float* __restrict__ wl, int* __restrict__ slotmap) {
  __shared__ int cnt[NEXP], cur[NEXP], flag;
  const int t = threadIdx.x;
  if (t < NEXP) cnt[t] = 0;
  if (t == 0) flag = 0;
  __syncthreads();
  // dtype detect: if int64, all high (odd) words are 0
  int lf = 0;
#pragma unroll
  for (int j = 0; j < 4; ++j) {
    int i = t + j * 1024;
    if (idx[2 * i + 1] != 0) lf = 1;
  }
  if (lf) atomicOr(&flag, 1);
  __syncthreads();
  const int is32 = flag;
  int e[8];
#pragma unroll
  for (int j = 0; j < 8; ++j) {
    int i = t + j * 1024;
    int ei = is32 ? idx[i] : idx[2 * i];
    e[j] = ei;
    atomicAdd(&cnt[ei], 1);
  }
  __syncthreads();
  if (t == 0) {
    int off = 0;
    for (int k = 0; k < NEXP; ++k) {
      cur[k] = off; offs_g[k] = off; counts_g[k] = cnt[k]; off += cnt[k];
    }
  }
  __syncthreads();
#pragma unroll
  for (int j = 0; j < 8; ++j) {
    int i = t + j * 1024;
    int n = i >> 1;
    int slot = atomicAdd(&cur[e[j]], 1);
    toks[slot] = n;
    wl[slot] = ew[i] * (amask[n] ? 1.0f : 0.0f);
    slotmap[i] = slot;
  }
}

// ---------------- grouped GEMM1: hid = relu(X[gather] @ down) ----------------
// 128x128 tile, BK=64, 256 thr / 4 waves (2Mx2N), per-wave 64x64 (acc[4][4]):
// 2.0 MFMA per ds_read_b128, 64KB LDS dbuf -> 2 blocks/CU (TLP hides tile drain).
// Single barrier + single vmcnt(0) per K-tile (race-free since R6).
// Expert->XCD colocation: blockIdx.x == XCD == expert.
__global__ __launch_bounds__(256, 4) void k_gemm_down(
    const unsigned short* __restrict__ x16, const unsigned short* __restrict__ bT,
    const int* __restrict__ counts, const int* __restrict__ offs,
    const int* __restrict__ toks, unsigned short* __restrict__ hid) {
  const int e = blockIdx.x;                 // expert == XCD
  const int cnt = counts[e];
  const int q = blockIdx.y;
  const int mt = q >> 4;                    // 0..63
  const int nt = q & 15;                    // 0..15 (DDIM/128)
  if (mt * 128 >= cnt) return;
  const int base = offs[e];
  __shared__ alignas(16) char lds[65536];   // A: 2x16KB @0, B: 2x16KB @32768
  const int tid = threadIdx.x;
  const int lane = tid & 63;
  const int wr = ((tid >> 7) & 1) * 64;     // wave M block (2)
  const int wc = ((tid >> 6) & 1) * 64;     // wave N block (2)

  // staging: LDS linear [128 rows][128B]; global col pre-swizzled so
  // LDS[row][c] = G[row][c ^ ((row&7)<<4)]   (rule #21)
  const char* gA[4]; const char* gB[4]; int sOff[4];
  {
    const int swcol = ((tid & 7) << 4) ^ (((tid >> 3) & 7) << 4);
#pragma unroll
    for (int s = 0; s < 4; ++s) {
      int row = s * 32 + (tid >> 3);
      int sl = mt * 128 + row; if (sl >= cnt) sl = cnt - 1;
      gA[s] = (const char*)(x16 + (size_t)toks[base + sl] * HDIM) + swcol;
      gB[s] = (const char*)(bT + (size_t)e * DDIM * HDIM + (size_t)(nt * 128 + row) * HDIM) + swcol;
      sOff[s] = s * 4096 + tid * 16;
    }
  }
  const int swz = (lane & 7) << 4;
  const int lo = (lane >> 4) << 4;
  int rowA[4], rowB[4];
#pragma unroll
  for (int m = 0; m < 4; ++m) rowA[m] = (wr + m * 16 + (lane & 15)) * 128;
#pragma unroll
  for (int n = 0; n < 4; ++n) rowB[n] = (wc + n * 16 + (lane & 15)) * 128;

  // prologue: stage K-tile 0 into buf0
#pragma unroll
  for (int s = 0; s < 4; ++s) {
    async16(lds + sOff[s], gA[s]);
    async16(lds + 32768 + sOff[s], gB[s]);
  }

  f32x4 acc[4][4] = {};
  for (int j = 0; j < 16; ++j) {
    WAIT_VM0();   // tile j's 8 loads landed (issued during tile j-1)
    BARRIER();    // all waves' reads of buf[(j-1)&1] retired (their lgkmcnt drained)
    char* curA = lds + ((j & 1) << 14);
    char* curB = lds + 32768 + ((j & 1) << 14);
    if (j < 15) {
      const int ko = (j + 1) << 7;
      char* nA = lds + ((~j & 1) << 14);
      char* nB = lds + 32768 + ((~j & 1) << 14);
#pragma unroll
      for (int s = 0; s < 4; ++s) {
        async16(nA + sOff[s], gA[s] + ko);
        async16(nB + sOff[s], gB[s] + ko);
      }
    }
#pragma unroll
    for (int ks = 0; ks < 2; ++ks) {
      const int cx = ((ks << 6) | lo) ^ swz;
      bf16x8 fa[4], fb[4];
#pragma unroll
      for (int n = 0; n < 4; ++n) fb[n] = *reinterpret_cast<const bf16x8*>(curB + rowB[n] + cx);
#pragma unroll
      for (int m = 0; m < 4; ++m) fa[m] = *reinterpret_cast<const bf16x8*>(curA + rowA[m] + cx);
      WAIT_LGKM0();
      __builtin_amdgcn_s_setprio(1);
#pragma unroll
      for (int m = 0; m < 4; ++m)
#pragma unroll
        for (int n = 0; n < 4; ++n)
          acc[m][n] = __builtin_amdgcn_mfma_f32_16x16x32_bf16(fa[m], fb[n], acc[m][n], 0, 0, 0);
      __builtin_amdgcn_s_setprio(0);
    }
  }

#pragma unroll
  for (int m = 0; m < 4; ++m) {
    int r0 = mt * 128 + wr + m * 16 + ((lane >> 4) * 4);
#pragma unroll
    for (int jj = 0; jj < 4; ++jj) {
      int r = r0 + jj;
      if (r < cnt) {
        unsigned short* dst = hid + (size_t)(base + r) * DDIM + nt * 128 + wc + (lane & 15);
#pragma unroll
        for (int n = 0; n < 4; ++n) {
          float v = acc[m][n][jj];
          dst[n * 16] = f2bf(v > 0.f ? v : 0.f);
        }
      }
    }
  }
}

// ---------------- grouped GEMM2: yw[slot] = hid[slot] @ up  (K=2048) ----------------
// Same geometry/pipeline. Expert->XCD colocation.
__global__ __launch_bounds__(256, 4) void k_gemm_up(
    const unsigned short* __restrict__ hid, const unsigned short* __restrict__ bT,
    const int* __restrict__ counts, const int* __restrict__ offs,
    unsigned short* __restrict__ yw) {
  const int e = blockIdx.x;                 // expert == XCD
  const int cnt = counts[e];
  const int q = blockIdx.y;
  const int mt = q >> 3;                    // 0..63
  const int nt = q & 7;                     // 0..7 (HDIM/128)
  if (mt * 128 >= cnt) return;
  const int base = offs[e];
  __shared__ alignas(16) char lds[65536];
  const int tid = threadIdx.x;
  const int lane = tid & 63;
  const int wr = ((tid >> 7) & 1) * 64;
  const int wc = ((tid >> 6) & 1) * 64;

  const char* gA[4]; const char* gB[4]; int sOff[4];
  {
    const int swcol = ((tid & 7) << 4) ^ (((tid >> 3) & 7) << 4);
#pragma unroll
    for (int s = 0; s < 4; ++s) {
      int row = s * 32 + (tid >> 3);
      int sl = mt * 128 + row; if (sl >= cnt) sl = cnt - 1;
      gA[s] = (const char*)(hid + (size_t)(base + sl) * DDIM) + swcol;
      gB[s] = (const char*)(bT + (size_t)e * HDIM * DDIM + (size_t)(nt * 128 + row) * DDIM) + swcol;
      sOff[s] = s * 4096 + tid * 16;
    }
  }
  const int swz = (lane & 7) << 4;
  const int lo = (lane >> 4) << 4;
  int rowA[4], rowB[4];
#pragma unroll
  for (int m = 0; m < 4; ++m) rowA[m] = (wr + m * 16 + (lane & 15)) * 128;
#pragma unroll
  for (int n = 0; n < 4; ++n) rowB[n] = (wc + n * 16 + (lane & 15)) * 128;

#pragma unroll
  for (int s = 0; s < 4; ++s) {
    async16(lds + sOff[s], gA[s]);
    async16(lds + 32768 + sOff[s], gB[s]);
  }

  f32x4 acc[4][4] = {};
  for (int j = 0; j < 32; ++j) {
    WAIT_VM0();
    BARRIER();
    char* curA = lds + ((j & 1) << 14);
    char* curB = lds + 32768 + ((j & 1) << 14);
    if (j < 31) {
      const int ko = (j + 1) << 7;
      char* nA = lds + ((~j & 1) << 14);
      char* nB = lds + 32768 + ((~j & 1) << 14);
#pragma unroll
      for (int s = 0; s < 4; ++s) {
        async16(nA + sOff[s], gA[s] + ko);
        async16(nB + sOff[s], gB[s] + ko);
      }
    }
#pragma unroll
    for (int ks = 0; ks < 2; ++ks) {
      const int cx = ((ks << 6) | lo) ^ swz;
      bf16x8 fa[4], fb[4];
#pragma unroll
      for (int n = 0; n < 4; ++n) fb[n] = *reinterpret_cast<const bf16x8*>(curB + rowB[n] + cx);
#pragma unroll
      for (int m = 0; m < 4; ++m) fa[m] = *reinterpret_cast<const bf16x8*>(curA + rowA[m] + cx);
      WAIT_LGKM0();
      __builtin_amdgcn_s_setprio(1);
#pragma unroll
      for (int m = 0; m < 4; ++m)
#pragma unroll
        for (int n = 0; n < 4; ++n)
          acc[m][n] = __builtin_amdgcn_mfma_f32_16x16x32_bf16(fa[m], fb[n], acc[m][n], 0, 0, 0);
      __builtin_amdgcn_s_setprio(0);
    }
  }

#pragma unroll
  for (int m = 0; m < 4; ++m) {
    int r0 = mt * 128 + wr + m * 16 + ((lane >> 4) * 4);
#pragma unroll
    for (int jj = 0; jj < 4; ++jj) {
      int r = r0 + jj;
      if (r < cnt) {
        unsigned short* dst = yw + (size_t)(base + r) * HDIM + nt * 128 + wc + (lane & 15);
#pragma unroll
        for (int n = 0; n < 4; ++n) dst[n * 16] = f2bf(acc[m][n][jj]);
      }
    }
  }
}

// ---------------- combine: out = x + w0*y0 + w1*y1 ----------------
__global__ __launch_bounds__(256) void k_combine(
    const float* __restrict__ x, const unsigned short* __restrict__ yw,
    const int* __restrict__ slotmap, const float* __restrict__ wl,
    float* __restrict__ out) {
  const int n = blockIdx.x;
  const int t = threadIdx.x;
  const int s0 = slotmap[2 * n], s1 = slotmap[2 * n + 1];
  const float w0 = wl[s0], w1 = wl[s1];
  float4 xv = reinterpret_cast<const float4*>(x + (size_t)n * HDIM)[t];
  ushort4 a0 = reinterpret_cast<const ushort4*>(yw + (size_t)s0 * HDIM)[t];
  ushort4 b0 = reinterpret_cast<const ushort4*>(yw + (size_t)s1 * HDIM)[t];
  float4 r;
  r.x = xv.x + w0 * bf2f(a0.x) + w1 * bf2f(b0.x);
  r.y = xv.y + w0 * bf2f(a0.y) + w1 * bf2f(b0.y);
  r.z = xv.z + w0 * bf2f(a0.z) + w1 * bf2f(b0.z);
  r.w = xv.w + w0 * bf2f(a0.w) + w1 * bf2f(b0.w);
  reinterpret_cast<float4*>(out + (size_t)n * HDIM)[t] = r;
}

extern "C" void kernel_launch(void* const* d_in, const int* in_sizes, int n_in,
                              void* d_out, int out_size, void* d_ws, size_t ws_size,
                              hipStream_t stream) {
  const float* x    = (const float*)d_in[0];
  const int* amask  = (const int*)d_in[1];
  const float* ew   = (const float*)d_in[2];
  const int* cidx   = (const int*)d_in[3];
  const float* dn   = (const float*)d_in[4];
  const float* up   = (const float*)d_in[5];
  float* out        = (float*)d_out;
  char* ws          = (char*)d_ws;

  const size_t X16_OFF = 0;
  const size_t DNT_OFF = X16_OFF + (size_t)NTOK * HDIM * 2;             // 8.4MB
  const size_t UPT_OFF = DNT_OFF + (size_t)NEXP * HDIM * DDIM * 2;      // +33.5MB
  const size_t HID_OFF = UPT_OFF + (size_t)NEXP * HDIM * DDIM * 2;      // +33.5MB
  const size_t MET_OFF = HID_OFF + (size_t)NASS * DDIM * 2;             // +33.5MB

  unsigned short* x16 = (unsigned short*)(ws + X16_OFF);
  unsigned short* dnT = (unsigned short*)(ws + DNT_OFF);
  unsigned short* upT = (unsigned short*)(ws + UPT_OFF);
  unsigned short* hid = (unsigned short*)(ws + HID_OFF);
  // yw ([NASS][HDIM] bf16, 16.8MB) aliases dnT: dnT dead after k_gemm_down
  unsigned short* yw  = (unsigned short*)(ws + DNT_OFF);
  int* counts  = (int*)(ws + MET_OFF);
  int* offs    = counts + 8;
  int* toks    = counts + 32;
  float* wl    = (float*)(toks + NASS);
  int* slotmap = (int*)(wl + NASS);

  k_prep<<<4096 + 16384 + 16384, 256, 0, stream>>>(x, x16, dn, dnT, up, upT);
  k_route<<<1, 1024, 0, stream>>>(cidx, ew, amask, counts, offs, toks, wl, slotmap);
  // blockIdx.x == XCD id (round-robin dispatch) == expert id
  k_gemm_down<<<dim3(8, 1024), 256, 0, stream>>>(x16, dnT, counts, offs, toks, hid);
  k_gemm_up<<<dim3(8, 512), 256, 0, stream>>>(hid, upT, counts, offs, yw);
  k_combine<<<NTOK, 256, 0, stream>>>(x, yw, slotmap, wl, out);
}

// Round 12
// 148.779 us; speedup vs baseline: 1.1573x; 1.0520x over previous
//
#include <hip/hip_runtime.h>
#include <stdint.h>

#define NTOK 4096
#define HDIM 1024
#define DDIM 2048
#define NEXP 8
#define NASS 8192   // NTOK * K (K=2)

typedef __attribute__((ext_vector_type(8))) short bf16x8;
typedef __attribute__((ext_vector_type(4))) float f32x4;

typedef __attribute__((address_space(1))) const unsigned int gu32;
typedef __attribute__((address_space(3))) unsigned int lu32;

// barrier that is ALSO a compiler memory fence (raw builtin is not; R5 raced)
#define BARRIER() asm volatile("s_barrier" ::: "memory")
#define WAIT_VM0() asm volatile("s_waitcnt vmcnt(0)" ::: "memory")
#define WAIT_LGKM0() do { asm volatile("s_waitcnt lgkmcnt(0)" ::: "memory"); \
                          __builtin_amdgcn_sched_barrier(0); } while (0)

__device__ __forceinline__ void async16(void* lds, const void* g) {
  __builtin_amdgcn_global_load_lds((gu32*)(uintptr_t)g, (lu32*)(uintptr_t)lds, 16, 0, 0);
}

__device__ __forceinline__ unsigned short f2bf(float f) {
  unsigned int u = __float_as_uint(f);
  return (unsigned short)((u + 0x7fffu + ((u >> 16) & 1u)) >> 16);
}
__device__ __forceinline__ float bf2f(unsigned short u) {
  return __uint_as_float(((unsigned int)u) << 16);
}
__device__ __forceinline__ unsigned int pack2(float lo, float hi) {
  return (unsigned int)f2bf(lo) | ((unsigned int)f2bf(hi) << 16);
}

// ---------------- prep: cvt_x + transpose(dn) + transpose(up), ONE launch ----------------
// 64x64 transpose tiles: 256B read segments, 128B write segments (R11 was 128B/64B
// -> 2.3 TB/s; small write segments were the bottleneck).
__device__ __forceinline__ void transpose64(const float* __restrict__ in,
                                            unsigned short* __restrict__ out,
                                            int R, int C, int e, int bk, int bn,
                                            float* tile, int tid) {
  const size_t mbase = (size_t)e * R * C;
  // read 64x64 fp32 tile: 16 threads x float4 per row, 16 rows per iter
#pragma unroll
  for (int it = 0; it < 4; ++it) {
    int row = it * 16 + (tid >> 4);
    int c4 = (tid & 15) * 4;
    float4 v = *reinterpret_cast<const float4*>(in + mbase + (size_t)(bk * 64 + row) * C + bn * 64 + c4);
    tile[row * 65 + c4 + 0] = v.x; tile[row * 65 + c4 + 1] = v.y;
    tile[row * 65 + c4 + 2] = v.z; tile[row * 65 + c4 + 3] = v.w;
  }
  __syncthreads();
  // write 64 rows of out[n][k]: 8 threads x ushort8(16B) per row, 32 rows per iter
#pragma unroll
  for (int it = 0; it < 2; ++it) {
    int n = it * 32 + (tid >> 3);
    int k8 = (tid & 7) * 8;
    uint4 o;
    o.x = pack2(tile[(k8 + 0) * 65 + n], tile[(k8 + 1) * 65 + n]);
    o.y = pack2(tile[(k8 + 2) * 65 + n], tile[(k8 + 3) * 65 + n]);
    o.z = pack2(tile[(k8 + 4) * 65 + n], tile[(k8 + 5) * 65 + n]);
    o.w = pack2(tile[(k8 + 6) * 65 + n], tile[(k8 + 7) * 65 + n]);
    *reinterpret_cast<uint4*>(out + mbase + (size_t)(bn * 64 + n) * R + bk * 64 + k8) = o;
  }
}

__global__ __launch_bounds__(256) void k_prep(
    const float* __restrict__ x, unsigned short* __restrict__ x16,
    const float* __restrict__ dn, unsigned short* __restrict__ dnT,
    const float* __restrict__ up, unsigned short* __restrict__ upT) {
  __shared__ float tile[64 * 65];
  const int b = blockIdx.x;
  const int tid = threadIdx.x;
  if (b < 2048) {
    // x fp32 -> bf16, 8 elems/thread (16B stores)
    int i = b * 2048 + tid * 8;
    float4 v0 = *reinterpret_cast<const float4*>(x + i);
    float4 v1 = *reinterpret_cast<const float4*>(x + i + 4);
    uint4 o;
    o.x = pack2(v0.x, v0.y); o.y = pack2(v0.z, v0.w);
    o.z = pack2(v1.x, v1.y); o.w = pack2(v1.z, v1.w);
    *reinterpret_cast<uint4*>(x16 + i) = o;
  } else if (b < 2048 + 4096) {
    // dn: [E][1024][2048] -> dnT [E][2048][1024]; 16x32 tiles of 64x64 per expert
    int idx = b - 2048;
    int e = idx >> 9, t = idx & 511;
    transpose64(dn, dnT, HDIM, DDIM, e, t & 15, t >> 4, tile, tid);
  } else {
    // up: [E][2048][1024] -> upT [E][1024][2048]; 32x16 tiles of 64x64 per expert
    int idx = b - (2048 + 4096);
    int e = idx >> 9, t = idx & 511;
    transpose64(up, upT, DDIM, HDIM, e, t & 31, t >> 5, tile, tid);
  }
}

// ---------------- routing: detect+count+scan+scatter in ONE block ----------------
__global__ __launch_bounds__(1024) void k_route(
    const int* __restrict__ idx, const float* __restrict__ ew,
    const int* __restrict__ amask,
    int* __restrict__ counts_g, int* __restrict__ offs_g,
    int* __restrict__ toks, float* __restrict__ wl, int* __restrict__ slotmap) {
  __shared__ int cnt[NEXP], cur[NEXP], flag;
  const int t = threadIdx.x;
  if (t < NEXP) cnt[t] = 0;
  if (t == 0) flag = 0;
  __syncthreads();
  // dtype detect: if int64, all high (odd) words are 0
  int lf = 0;
#pragma unroll
  for (int j = 0; j < 4; ++j) {
    int i = t + j * 1024;
    if (idx[2 * i + 1] != 0) lf = 1;
  }
  if (lf) atomicOr(&flag, 1);
  __syncthreads();
  const int is32 = flag;
  int e[8];
#pragma unroll
  for (int j = 0; j < 8; ++j) {
    int i = t + j * 1024;
    int ei = is32 ? idx[i] : idx[2 * i];
    e[j] = ei;
    atomicAdd(&cnt[ei], 1);
  }
  __syncthreads();
  if (t == 0) {
    int off = 0;
    for (int k = 0; k < NEXP; ++k) {
      cur[k] = off; offs_g[k] = off; counts_g[k] = cnt[k]; off += cnt[k];
    }
  }
  __syncthreads();
#pragma unroll
  for (int j = 0; j < 8; ++j) {
    int i = t + j * 1024;
    int n = i >> 1;
    int slot = atomicAdd(&cur[e[j]], 1);
    toks[slot] = n;
    wl[slot] = ew[i] * (amask[n] ? 1.0f : 0.0f);
    slotmap[i] = slot;
  }
}

// ---------------- grouped GEMM1: hid = relu(X[gather] @ down) ----------------
// 128x128 tile, BK=64, 256 thr / 4 waves (2Mx2N), per-wave 64x64 (acc[4][4]):
// 2.0 MFMA per ds_read_b128, 64KB LDS dbuf -> 2 blocks/CU.
// Single barrier + single vmcnt(0) per K-tile (race-free since R6).
// Expert->XCD colocation: blockIdx.x == XCD == expert.
__global__ __launch_bounds__(256, 4) void k_gemm_down(
    const unsigned short* __restrict__ x16, const unsigned short* __restrict__ bT,
    const int* __restrict__ counts, const int* __restrict__ offs,
    const int* __restrict__ toks, unsigned short* __restrict__ hid) {
  const int e = blockIdx.x;                 // expert == XCD
  const int cnt = counts[e];
  const int q = blockIdx.y;
  const int mt = q >> 4;                    // 0..63
  const int nt = q & 15;                    // 0..15 (DDIM/128)
  if (mt * 128 >= cnt) return;
  const int base = offs[e];
  __shared__ alignas(16) char lds[65536];   // A: 2x16KB @0, B: 2x16KB @32768
  const int tid = threadIdx.x;
  const int lane = tid & 63;
  const int wr = ((tid >> 7) & 1) * 64;     // wave M block (2)
  const int wc = ((tid >> 6) & 1) * 64;     // wave N block (2)

  const char* gA[4]; const char* gB[4]; int sOff[4];
  {
    const int swcol = ((tid & 7) << 4) ^ (((tid >> 3) & 7) << 4);
#pragma unroll
    for (int s = 0; s < 4; ++s) {
      int row = s * 32 + (tid >> 3);
      int sl = mt * 128 + row; if (sl >= cnt) sl = cnt - 1;
      gA[s] = (const char*)(x16 + (size_t)toks[base + sl] * HDIM) + swcol;
      gB[s] = (const char*)(bT + (size_t)e * DDIM * HDIM + (size_t)(nt * 128 + row) * HDIM) + swcol;
      sOff[s] = s * 4096 + tid * 16;
    }
  }
  const int swz = (lane & 7) << 4;
  const int lo = (lane >> 4) << 4;
  int rowA[4], rowB[4];
#pragma unroll
  for (int m = 0; m < 4; ++m) rowA[m] = (wr + m * 16 + (lane & 15)) * 128;
#pragma unroll
  for (int n = 0; n < 4; ++n) rowB[n] = (wc + n * 16 + (lane & 15)) * 128;

#pragma unroll
  for (int s = 0; s < 4; ++s) {
    async16(lds + sOff[s], gA[s]);
    async16(lds + 32768 + sOff[s], gB[s]);
  }

  f32x4 acc[4][4] = {};
  for (int j = 0; j < 16; ++j) {
    WAIT_VM0();
    BARRIER();
    char* curA = lds + ((j & 1) << 14);
    char* curB = lds + 32768 + ((j & 1) << 14);
    if (j < 15) {
      const int ko = (j + 1) << 7;
      char* nA = lds + ((~j & 1) << 14);
      char* nB = lds + 32768 + ((~j & 1) << 14);
#pragma unroll
      for (int s = 0; s < 4; ++s) {
        async16(nA + sOff[s], gA[s] + ko);
        async16(nB + sOff[s], gB[s] + ko);
      }
    }
#pragma unroll
    for (int ks = 0; ks < 2; ++ks) {
      const int cx = ((ks << 6) | lo) ^ swz;
      bf16x8 fa[4], fb[4];
#pragma unroll
      for (int n = 0; n < 4; ++n) fb[n] = *reinterpret_cast<const bf16x8*>(curB + rowB[n] + cx);
#pragma unroll
      for (int m = 0; m < 4; ++m) fa[m] = *reinterpret_cast<const bf16x8*>(curA + rowA[m] + cx);
      WAIT_LGKM0();
      __builtin_amdgcn_s_setprio(1);
#pragma unroll
      for (int m = 0; m < 4; ++m)
#pragma unroll
        for (int n = 0; n < 4; ++n)
          acc[m][n] = __builtin_amdgcn_mfma_f32_16x16x32_bf16(fa[m], fb[n], acc[m][n], 0, 0, 0);
      __builtin_amdgcn_s_setprio(0);
    }
  }

#pragma unroll
  for (int m = 0; m < 4; ++m) {
    int r0 = mt * 128 + wr + m * 16 + ((lane >> 4) * 4);
#pragma unroll
    for (int jj = 0; jj < 4; ++jj) {
      int r = r0 + jj;
      if (r < cnt) {
        unsigned short* dst = hid + (size_t)(base + r) * DDIM + nt * 128 + wc + (lane & 15);
#pragma unroll
        for (int n = 0; n < 4; ++n) {
          float v = acc[m][n][jj];
          dst[n * 16] = f2bf(v > 0.f ? v : 0.f);
        }
      }
    }
  }
}

// ---------------- grouped GEMM2: yw[slot] = hid[slot] @ up  (K=2048) ----------------
__global__ __launch_bounds__(256, 4) void k_gemm_up(
    const unsigned short* __restrict__ hid, const unsigned short* __restrict__ bT,
    const int* __restrict__ counts, const int* __restrict__ offs,
    unsigned short* __restrict__ yw) {
  const int e = blockIdx.x;                 // expert == XCD
  const int cnt = counts[e];
  const int q = blockIdx.y;
  const int mt = q >> 3;                    // 0..63
  const int nt = q & 7;                     // 0..7 (HDIM/128)
  if (mt * 128 >= cnt) return;
  const int base = offs[e];
  __shared__ alignas(16) char lds[65536];
  const int tid = threadIdx.x;
  const int lane = tid & 63;
  const int wr = ((tid >> 7) & 1) * 64;
  const int wc = ((tid >> 6) & 1) * 64;

  const char* gA[4]; const char* gB[4]; int sOff[4];
  {
    const int swcol = ((tid & 7) << 4) ^ (((tid >> 3) & 7) << 4);
#pragma unroll
    for (int s = 0; s < 4; ++s) {
      int row = s * 32 + (tid >> 3);
      int sl = mt * 128 + row; if (sl >= cnt) sl = cnt - 1;
      gA[s] = (const char*)(hid + (size_t)(base + sl) * DDIM) + swcol;
      gB[s] = (const char*)(bT + (size_t)e * HDIM * DDIM + (size_t)(nt * 128 + row) * DDIM) + swcol;
      sOff[s] = s * 4096 + tid * 16;
    }
  }
  const int swz = (lane & 7) << 4;
  const int lo = (lane >> 4) << 4;
  int rowA[4], rowB[4];
#pragma unroll
  for (int m = 0; m < 4; ++m) rowA[m] = (wr + m * 16 + (lane & 15)) * 128;
#pragma unroll
  for (int n = 0; n < 4; ++n) rowB[n] = (wc + n * 16 + (lane & 15)) * 128;

#pragma unroll
  for (int s = 0; s < 4; ++s) {
    async16(lds + sOff[s], gA[s]);
    async16(lds + 32768 + sOff[s], gB[s]);
  }

  f32x4 acc[4][4] = {};
  for (int j = 0; j < 32; ++j) {
    WAIT_VM0();
    BARRIER();
    char* curA = lds + ((j & 1) << 14);
    char* curB = lds + 32768 + ((j & 1) << 14);
    if (j < 31) {
      const int ko = (j + 1) << 7;
      char* nA = lds + ((~j & 1) << 14);
      char* nB = lds + 32768 + ((~j & 1) << 14);
#pragma unroll
      for (int s = 0; s < 4; ++s) {
        async16(nA + sOff[s], gA[s] + ko);
        async16(nB + sOff[s], gB[s] + ko);
      }
    }
#pragma unroll
    for (int ks = 0; ks < 2; ++ks) {
      const int cx = ((ks << 6) | lo) ^ swz;
      bf16x8 fa[4], fb[4];
#pragma unroll
      for (int n = 0; n < 4; ++n) fb[n] = *reinterpret_cast<const bf16x8*>(curB + rowB[n] + cx);
#pragma unroll
      for (int m = 0; m < 4; ++m) fa[m] = *reinterpret_cast<const bf16x8*>(curA + rowA[m] + cx);
      WAIT_LGKM0();
      __builtin_amdgcn_s_setprio(1);
#pragma unroll
      for (int m = 0; m < 4; ++m)
#pragma unroll
        for (int n = 0; n < 4; ++n)
          acc[m][n] = __builtin_amdgcn_mfma_f32_16x16x32_bf16(fa[m], fb[n], acc[m][n], 0, 0, 0);
      __builtin_amdgcn_s_setprio(0);
    }
  }

#pragma unroll
  for (int m = 0; m < 4; ++m) {
    int r0 = mt * 128 + wr + m * 16 + ((lane >> 4) * 4);
#pragma unroll
    for (int jj = 0; jj < 4; ++jj) {
      int r = r0 + jj;
      if (r < cnt) {
        unsigned short* dst = yw + (size_t)(base + r) * HDIM + nt * 128 + wc + (lane & 15);
#pragma unroll
        for (int n = 0; n < 4; ++n) dst[n * 16] = f2bf(acc[m][n][jj]);
      }
    }
  }
}

// ---------------- combine: out = x + w0*y0 + w1*y1 ----------------
__global__ __launch_bounds__(256) void k_combine(
    const float* __restrict__ x, const unsigned short* __restrict__ yw,
    const int* __restrict__ slotmap, const float* __restrict__ wl,
    float* __restrict__ out) {
  const int n = blockIdx.x;
  const int t = threadIdx.x;
  const int s0 = slotmap[2 * n], s1 = slotmap[2 * n + 1];
  const float w0 = wl[s0], w1 = wl[s1];
  float4 xv = reinterpret_cast<const float4*>(x + (size_t)n * HDIM)[t];
  ushort4 a0 = reinterpret_cast<const ushort4*>(yw + (size_t)s0 * HDIM)[t];
  ushort4 b0 = reinterpret_cast<const ushort4*>(yw + (size_t)s1 * HDIM)[t];
  float4 r;
  r.x = xv.x + w0 * bf2f(a0.x) + w1 * bf2f(b0.x);
  r.y = xv.y + w0 * bf2f(a0.y) + w1 * bf2f(b0.y);
  r.z = xv.z + w0 * bf2f(a0.z) + w1 * bf2f(b0.z);
  r.w = xv.w + w0 * bf2f(a0.w) + w1 * bf2f(b0.w);
  reinterpret_cast<float4*>(out + (size_t)n * HDIM)[t] = r;
}

extern "C" void kernel_launch(void* const* d_in, const int* in_sizes, int n_in,
                              void* d_out, int out_size, void* d_ws, size_t ws_size,
                              hipStream_t stream) {
  const float* x    = (const float*)d_in[0];
  const int* amask  = (const int*)d_in[1];
  const float* ew   = (const float*)d_in[2];
  const int* cidx   = (const int*)d_in[3];
  const float* dn   = (const float*)d_in[4];
  const float* up   = (const float*)d_in[5];
  float* out        = (float*)d_out;
  char* ws          = (char*)d_ws;

  const size_t X16_OFF = 0;
  const size_t DNT_OFF = X16_OFF + (size_t)NTOK * HDIM * 2;             // 8.4MB
  const size_t UPT_OFF = DNT_OFF + (size_t)NEXP * HDIM * DDIM * 2;      // +33.5MB
  const size_t HID_OFF = UPT_OFF + (size_t)NEXP * HDIM * DDIM * 2;      // +33.5MB
  const size_t MET_OFF = HID_OFF + (size_t)NASS * DDIM * 2;             // +33.5MB

  unsigned short* x16 = (unsigned short*)(ws + X16_OFF);
  unsigned short* dnT = (unsigned short*)(ws + DNT_OFF);
  unsigned short* upT = (unsigned short*)(ws + UPT_OFF);
  unsigned short* hid = (unsigned short*)(ws + HID_OFF);
  // yw ([NASS][HDIM] bf16, 16.8MB) aliases dnT: dnT dead after k_gemm_down
  unsigned short* yw  = (unsigned short*)(ws + DNT_OFF);
  int* counts  = (int*)(ws + MET_OFF);
  int* offs    = counts + 8;
  int* toks    = counts + 32;
  float* wl    = (float*)(toks + NASS);
  int* slotmap = (int*)(wl + NASS);

  k_prep<<<2048 + 4096 + 4096, 256, 0, stream>>>(x, x16, dn, dnT, up, upT);
  k_route<<<1, 1024, 0, stream>>>(cidx, ew, amask, counts, offs, toks, wl, slotmap);
  // blockIdx.x == XCD id (round-robin dispatch) == expert id
  k_gemm_down<<<dim3(8, 1024), 256, 0, stream>>>(x16, dnT, counts, offs, toks, hid);
  k_gemm_up<<<dim3(8, 512), 256, 0, stream>>>(hid, upT, counts, offs, yw);
  k_combine<<<NTOK, 256, 0, stream>>>(x, yw, slotmap, wl, out);
}

// Round 13
// 147.237 us; speedup vs baseline: 1.1694x; 1.0105x over previous
//
#include <hip/hip_runtime.h>
#include <stdint.h>

#define NTOK 4096
#define HDIM 1024
#define DDIM 2048
#define NEXP 8
#define NASS 8192   // NTOK * K (K=2)

typedef __attribute__((ext_vector_type(8))) short bf16x8;
typedef __attribute__((ext_vector_type(4))) float f32x4;

typedef __attribute__((address_space(1))) const unsigned int gu32;
typedef __attribute__((address_space(3))) unsigned int lu32;

// barrier that is ALSO a compiler memory fence (raw builtin is not; R5 raced)
#define BARRIER() asm volatile("s_barrier" ::: "memory")
#define WAIT_VM0() asm volatile("s_waitcnt vmcnt(0)" ::: "memory")
#define WAIT_LGKM0() do { asm volatile("s_waitcnt lgkmcnt(0)" ::: "memory"); \
                          __builtin_amdgcn_sched_barrier(0); } while (0)

__device__ __forceinline__ void async16(void* lds, const void* g) {
  __builtin_amdgcn_global_load_lds((gu32*)(uintptr_t)g, (lu32*)(uintptr_t)lds, 16, 0, 0);
}

__device__ __forceinline__ unsigned short f2bf(float f) {
  unsigned int u = __float_as_uint(f);
  return (unsigned short)((u + 0x7fffu + ((u >> 16) & 1u)) >> 16);
}
__device__ __forceinline__ float bf2f(unsigned short u) {
  return __uint_as_float(((unsigned int)u) << 16);
}
__device__ __forceinline__ unsigned int pack2(float lo, float hi) {
  return (unsigned int)f2bf(lo) | ((unsigned int)f2bf(hi) << 16);
}

// ---------------- prep: cvt_x + transpose(dn) + transpose(up), ONE launch ----------------
// 128x128 fp32 tiles: 16 outstanding float4 loads/thread (deep MLP), 512B read
// segments, 256B write segments. R12's 64-tiles (4 loads/thread) stuck at 2.4 TB/s.
__device__ __forceinline__ void transpose128(const float* __restrict__ in,
                                             unsigned short* __restrict__ out,
                                             int R, int C, int e, int bk, int bn,
                                             float* tile, int tid) {
  const size_t mbase = (size_t)e * R * C;
  // read 128x128 fp32: 16 iters x (8 rows x 32 lanes x float4); 512B/row segment
#pragma unroll
  for (int it = 0; it < 16; ++it) {
    int row = it * 8 + (tid >> 5);
    int c4 = (tid & 31) * 4;
    float4 v = *reinterpret_cast<const float4*>(
        in + mbase + (size_t)(bk * 128 + row) * C + bn * 128 + c4);
    tile[row * 129 + c4 + 0] = v.x; tile[row * 129 + c4 + 1] = v.y;
    tile[row * 129 + c4 + 2] = v.z; tile[row * 129 + c4 + 3] = v.w;
  }
  __syncthreads();
  // write: 8 iters x (16 n-rows x 16 lanes x 8 bf16); 256B/row segment
#pragma unroll
  for (int it = 0; it < 8; ++it) {
    int n = it * 16 + (tid >> 4);
    int k8 = (tid & 15) * 8;
    uint4 o;
    o.x = pack2(tile[(k8 + 0) * 129 + n], tile[(k8 + 1) * 129 + n]);
    o.y = pack2(tile[(k8 + 2) * 129 + n], tile[(k8 + 3) * 129 + n]);
    o.z = pack2(tile[(k8 + 4) * 129 + n], tile[(k8 + 5) * 129 + n]);
    o.w = pack2(tile[(k8 + 6) * 129 + n], tile[(k8 + 7) * 129 + n]);
    *reinterpret_cast<uint4*>(out + mbase + (size_t)(bn * 128 + n) * R + bk * 128 + k8) = o;
  }
}

__global__ __launch_bounds__(256) void k_prep(
    const float* __restrict__ x, unsigned short* __restrict__ x16,
    const float* __restrict__ dn, unsigned short* __restrict__ dnT,
    const float* __restrict__ up, unsigned short* __restrict__ upT) {
  __shared__ float tile[128 * 129];
  const int b = blockIdx.x;
  const int tid = threadIdx.x;
  if (b < 1024) {
    // dn: [E][1024][2048] -> dnT [E][2048][1024]; 8x16 tiles of 128 per expert
    int e = b >> 7, t = b & 127;
    transpose128(dn, dnT, HDIM, DDIM, e, t & 7, t >> 3, tile, tid);
  } else if (b < 2048) {
    // up: [E][2048][1024] -> upT [E][1024][2048]; 16x8 tiles of 128 per expert
    int idx = b - 1024;
    int e = idx >> 7, t = idx & 127;
    transpose128(up, upT, DDIM, HDIM, e, t & 15, t >> 4, tile, tid);
  } else {
    // x fp32 -> bf16, 8 elems/thread (16B stores)
    int i = (b - 2048) * 2048 + tid * 8;
    float4 v0 = *reinterpret_cast<const float4*>(x + i);
    float4 v1 = *reinterpret_cast<const float4*>(x + i + 4);
    uint4 o;
    o.x = pack2(v0.x, v0.y); o.y = pack2(v0.z, v0.w);
    o.z = pack2(v1.x, v1.y); o.w = pack2(v1.z, v1.w);
    *reinterpret_cast<uint4*>(x16 + i) = o;
  }
}

// ---------------- routing: detect+count+scan+scatter in ONE block ----------------
__global__ __launch_bounds__(1024) void k_route(
    const int* __restrict__ idx, const float* __restrict__ ew,
    const int* __restrict__ amask,
    int* __restrict__ counts_g, int* __restrict__ offs_g,
    int* __restrict__ toks, float* __restrict__ wl, int* __restrict__ slotmap) {
  __shared__ int cnt[NEXP], cur[NEXP], flag;
  const int t = threadIdx.x;
  if (t < NEXP) cnt[t] = 0;
  if (t == 0) flag = 0;
  __syncthreads();
  // dtype detect: if int64, all high (odd) words are 0
  int lf = 0;
#pragma unroll
  for (int j = 0; j < 4; ++j) {
    int i = t + j * 1024;
    if (idx[2 * i + 1] != 0) lf = 1;
  }
  if (lf) atomicOr(&flag, 1);
  __syncthreads();
  const int is32 = flag;
  int e[8];
#pragma unroll
  for (int j = 0; j < 8; ++j) {
    int i = t + j * 1024;
    int ei = is32 ? idx[i] : idx[2 * i];
    e[j] = ei;
    atomicAdd(&cnt[ei], 1);
  }
  __syncthreads();
  if (t == 0) {
    int off = 0;
    for (int k = 0; k < NEXP; ++k) {
      cur[k] = off; offs_g[k] = off; counts_g[k] = cnt[k]; off += cnt[k];
    }
  }
  __syncthreads();
#pragma unroll
  for (int j = 0; j < 8; ++j) {
    int i = t + j * 1024;
    int n = i >> 1;
    int slot = atomicAdd(&cur[e[j]], 1);
    toks[slot] = n;
    wl[slot] = ew[i] * (amask[n] ? 1.0f : 0.0f);
    slotmap[i] = slot;
  }
}

// ---------------- grouped GEMM1: hid = relu(X[gather] @ down) ----------------
// 128x128 tile, BK=64, 256 thr / 4 waves (2Mx2N), per-wave 64x64 (acc[4][4]):
// 2.0 MFMA per ds_read_b128, 64KB LDS dbuf -> 2 blocks/CU.
// Single barrier + single vmcnt(0) per K-tile (race-free since R6).
// Expert->XCD colocation: blockIdx.x == XCD == expert.
__global__ __launch_bounds__(256, 4) void k_gemm_down(
    const unsigned short* __restrict__ x16, const unsigned short* __restrict__ bT,
    const int* __restrict__ counts, const int* __restrict__ offs,
    const int* __restrict__ toks, unsigned short* __restrict__ hid) {
  const int e = blockIdx.x;                 // expert == XCD
  const int cnt = counts[e];
  const int q = blockIdx.y;
  const int mt = q >> 4;                    // 0..63
  const int nt = q & 15;                    // 0..15 (DDIM/128)
  if (mt * 128 >= cnt) return;
  const int base = offs[e];
  __shared__ alignas(16) char lds[65536];   // A: 2x16KB @0, B: 2x16KB @32768
  const int tid = threadIdx.x;
  const int lane = tid & 63;
  const int wr = ((tid >> 7) & 1) * 64;     // wave M block (2)
  const int wc = ((tid >> 6) & 1) * 64;     // wave N block (2)

  const char* gA[4]; const char* gB[4]; int sOff[4];
  {
    const int swcol = ((tid & 7) << 4) ^ (((tid >> 3) & 7) << 4);
#pragma unroll
    for (int s = 0; s < 4; ++s) {
      int row = s * 32 + (tid >> 3);
      int sl = mt * 128 + row; if (sl >= cnt) sl = cnt - 1;
      gA[s] = (const char*)(x16 + (size_t)toks[base + sl] * HDIM) + swcol;
      gB[s] = (const char*)(bT + (size_t)e * DDIM * HDIM + (size_t)(nt * 128 + row) * HDIM) + swcol;
      sOff[s] = s * 4096 + tid * 16;
    }
  }
  const int swz = (lane & 7) << 4;
  const int lo = (lane >> 4) << 4;
  int rowA[4], rowB[4];
#pragma unroll
  for (int m = 0; m < 4; ++m) rowA[m] = (wr + m * 16 + (lane & 15)) * 128;
#pragma unroll
  for (int n = 0; n < 4; ++n) rowB[n] = (wc + n * 16 + (lane & 15)) * 128;

#pragma unroll
  for (int s = 0; s < 4; ++s) {
    async16(lds + sOff[s], gA[s]);
    async16(lds + 32768 + sOff[s], gB[s]);
  }

  f32x4 acc[4][4] = {};
  for (int j = 0; j < 16; ++j) {
    WAIT_VM0();
    BARRIER();
    char* curA = lds + ((j & 1) << 14);
    char* curB = lds + 32768 + ((j & 1) << 14);
    if (j < 15) {
      const int ko = (j + 1) << 7;
      char* nA = lds + ((~j & 1) << 14);
      char* nB = lds + 32768 + ((~j & 1) << 14);
#pragma unroll
      for (int s = 0; s < 4; ++s) {
        async16(nA + sOff[s], gA[s] + ko);
        async16(nB + sOff[s], gB[s] + ko);
      }
    }
#pragma unroll
    for (int ks = 0; ks < 2; ++ks) {
      const int cx = ((ks << 6) | lo) ^ swz;
      bf16x8 fa[4], fb[4];
#pragma unroll
      for (int n = 0; n < 4; ++n) fb[n] = *reinterpret_cast<const bf16x8*>(curB + rowB[n] + cx);
#pragma unroll
      for (int m = 0; m < 4; ++m) fa[m] = *reinterpret_cast<const bf16x8*>(curA + rowA[m] + cx);
      WAIT_LGKM0();
      __builtin_amdgcn_s_setprio(1);
#pragma unroll
      for (int m = 0; m < 4; ++m)
#pragma unroll
        for (int n = 0; n < 4; ++n)
          acc[m][n] = __builtin_amdgcn_mfma_f32_16x16x32_bf16(fa[m], fb[n], acc[m][n], 0, 0, 0);
      __builtin_amdgcn_s_setprio(0);
    }
  }

#pragma unroll
  for (int m = 0; m < 4; ++m) {
    int r0 = mt * 128 + wr + m * 16 + ((lane >> 4) * 4);
#pragma unroll
    for (int jj = 0; jj < 4; ++jj) {
      int r = r0 + jj;
      if (r < cnt) {
        unsigned short* dst = hid + (size_t)(base + r) * DDIM + nt * 128 + wc + (lane & 15);
#pragma unroll
        for (int n = 0; n < 4; ++n) {
          float v = acc[m][n][jj];
          dst[n * 16] = f2bf(v > 0.f ? v : 0.f);
        }
      }
    }
  }
}

// ---------------- grouped GEMM2: yw[slot] = hid[slot] @ up  (K=2048) ----------------
__global__ __launch_bounds__(256, 4) void k_gemm_up(
    const unsigned short* __restrict__ hid, const unsigned short* __restrict__ bT,
    const int* __restrict__ counts, const int* __restrict__ offs,
    unsigned short* __restrict__ yw) {
  const int e = blockIdx.x;                 // expert == XCD
  const int cnt = counts[e];
  const int q = blockIdx.y;
  const int mt = q >> 3;                    // 0..63
  const int nt = q & 7;                     // 0..7 (HDIM/128)
  if (mt * 128 >= cnt) return;
  const int base = offs[e];
  __shared__ alignas(16) char lds[65536];
  const int tid = threadIdx.x;
  const int lane = tid & 63;
  const int wr = ((tid >> 7) & 1) * 64;
  const int wc = ((tid >> 6) & 1) * 64;

  const char* gA[4]; const char* gB[4]; int sOff[4];
  {
    const int swcol = ((tid & 7) << 4) ^ (((tid >> 3) & 7) << 4);
#pragma unroll
    for (int s = 0; s < 4; ++s) {
      int row = s * 32 + (tid >> 3);
      int sl = mt * 128 + row; if (sl >= cnt) sl = cnt - 1;
      gA[s] = (const char*)(hid + (size_t)(base + sl) * DDIM) + swcol;
      gB[s] = (const char*)(bT + (size_t)e * HDIM * DDIM + (size_t)(nt * 128 + row) * DDIM) + swcol;
      sOff[s] = s * 4096 + tid * 16;
    }
  }
  const int swz = (lane & 7) << 4;
  const int lo = (lane >> 4) << 4;
  int rowA[4], rowB[4];
#pragma unroll
  for (int m = 0; m < 4; ++m) rowA[m] = (wr + m * 16 + (lane & 15)) * 128;
#pragma unroll
  for (int n = 0; n < 4; ++n) rowB[n] = (wc + n * 16 + (lane & 15)) * 128;

#pragma unroll
  for (int s = 0; s < 4; ++s) {
    async16(lds + sOff[s], gA[s]);
    async16(lds + 32768 + sOff[s], gB[s]);
  }

  f32x4 acc[4][4] = {};
  for (int j = 0; j < 32; ++j) {
    WAIT_VM0();
    BARRIER();
    char* curA = lds + ((j & 1) << 14);
    char* curB = lds + 32768 + ((j & 1) << 14);
    if (j < 31) {
      const int ko = (j + 1) << 7;
      char* nA = lds + ((~j & 1) << 14);
      char* nB = lds + 32768 + ((~j & 1) << 14);
#pragma unroll
      for (int s = 0; s < 4; ++s) {
        async16(nA + sOff[s], gA[s] + ko);
        async16(nB + sOff[s], gB[s] + ko);
      }
    }
#pragma unroll
    for (int ks = 0; ks < 2; ++ks) {
      const int cx = ((ks << 6) | lo) ^ swz;
      bf16x8 fa[4], fb[4];
#pragma unroll
      for (int n = 0; n < 4; ++n) fb[n] = *reinterpret_cast<const bf16x8*>(curB + rowB[n] + cx);
#pragma unroll
      for (int m = 0; m < 4; ++m) fa[m] = *reinterpret_cast<const bf16x8*>(curA + rowA[m] + cx);
      WAIT_LGKM0();
      __builtin_amdgcn_s_setprio(1);
#pragma unroll
      for (int m = 0; m < 4; ++m)
#pragma unroll
        for (int n = 0; n < 4; ++n)
          acc[m][n] = __builtin_amdgcn_mfma_f32_16x16x32_bf16(fa[m], fb[n], acc[m][n], 0, 0, 0);
      __builtin_amdgcn_s_setprio(0);
    }
  }

#pragma unroll
  for (int m = 0; m < 4; ++m) {
    int r0 = mt * 128 + wr + m * 16 + ((lane >> 4) * 4);
#pragma unroll
    for (int jj = 0; jj < 4; ++jj) {
      int r = r0 + jj;
      if (r < cnt) {
        unsigned short* dst = yw + (size_t)(base + r) * HDIM + nt * 128 + wc + (lane & 15);
#pragma unroll
        for (int n = 0; n < 4; ++n) dst[n * 16] = f2bf(acc[m][n][jj]);
      }
    }
  }
}

// ---------------- combine: out = x + w0*y0 + w1*y1 ----------------
__global__ __launch_bounds__(256) void k_combine(
    const float* __restrict__ x, const unsigned short* __restrict__ yw,
    const int* __restrict__ slotmap, const float* __restrict__ wl,
    float* __restrict__ out) {
  const int n = blockIdx.x;
  const int t = threadIdx.x;
  const int s0 = slotmap[2 * n], s1 = slotmap[2 * n + 1];
  const float w0 = wl[s0], w1 = wl[s1];
  float4 xv = reinterpret_cast<const float4*>(x + (size_t)n * HDIM)[t];
  ushort4 a0 = reinterpret_cast<const ushort4*>(yw + (size_t)s0 * HDIM)[t];
  ushort4 b0 = reinterpret_cast<const ushort4*>(yw + (size_t)s1 * HDIM)[t];
  float4 r;
  r.x = xv.x + w0 * bf2f(a0.x) + w1 * bf2f(b0.x);
  r.y = xv.y + w0 * bf2f(a0.y) + w1 * bf2f(b0.y);
  r.z = xv.z + w0 * bf2f(a0.z) + w1 * bf2f(b0.z);
  r.w = xv.w + w0 * bf2f(a0.w) + w1 * bf2f(b0.w);
  reinterpret_cast<float4*>(out + (size_t)n * HDIM)[t] = r;
}

extern "C" void kernel_launch(void* const* d_in, const int* in_sizes, int n_in,
                              void* d_out, int out_size, void* d_ws, size_t ws_size,
                              hipStream_t stream) {
  const float* x    = (const float*)d_in[0];
  const int* amask  = (const int*)d_in[1];
  const float* ew   = (const float*)d_in[2];
  const int* cidx   = (const int*)d_in[3];
  const float* dn   = (const float*)d_in[4];
  const float* up   = (const float*)d_in[5];
  float* out        = (float*)d_out;
  char* ws          = (char*)d_ws;

  const size_t X16_OFF = 0;
  const size_t DNT_OFF = X16_OFF + (size_t)NTOK * HDIM * 2;             // 8.4MB
  const size_t UPT_OFF = DNT_OFF + (size_t)NEXP * HDIM * DDIM * 2;      // +33.5MB
  const size_t HID_OFF = UPT_OFF + (size_t)NEXP * HDIM * DDIM * 2;      // +33.5MB
  const size_t MET_OFF = HID_OFF + (size_t)NASS * DDIM * 2;             // +33.5MB

  unsigned short* x16 = (unsigned short*)(ws + X16_OFF);
  unsigned short* dnT = (unsigned short*)(ws + DNT_OFF);
  unsigned short* upT = (unsigned short*)(ws + UPT_OFF);
  unsigned short* hid = (unsigned short*)(ws + HID_OFF);
  // yw ([NASS][HDIM] bf16, 16.8MB) aliases dnT: dnT dead after k_gemm_down
  unsigned short* yw  = (unsigned short*)(ws + DNT_OFF);
  int* counts  = (int*)(ws + MET_OFF);
  int* offs    = counts + 8;
  int* toks    = counts + 32;
  float* wl    = (float*)(toks + NASS);
  int* slotmap = (int*)(wl + NASS);

  k_prep<<<1024 + 1024 + 2048, 256, 0, stream>>>(x, x16, dn, dnT, up, upT);
  k_route<<<1, 1024, 0, stream>>>(cidx, ew, amask, counts, offs, toks, wl, slotmap);
  // blockIdx.x == XCD id (round-robin dispatch) == expert id
  k_gemm_down<<<dim3(8, 1024), 256, 0, stream>>>(x16, dnT, counts, offs, toks, hid);
  k_gemm_up<<<dim3(8, 512), 256, 0, stream>>>(hid, upT, counts, offs, yw);
  k_combine<<<NTOK, 256, 0, stream>>>(x, yw, slotmap, wl, out);
}